// Round 1
// baseline (3935.000 us; speedup 1.0000x reference)
//
#include <hip/hip_runtime.h>

// ---------------- kernels ----------------

__global__ void k_deg(const int* __restrict__ dst, float* __restrict__ deg, int E) {
    int e = blockIdx.x * 256 + threadIdx.x;
    if (e < E) atomicAdd(&deg[dst[e]], 1.0f);
}

// deg -> dinv in place; also count nodes per graph
__global__ void k_node(float* __restrict__ deg_dinv, const int* __restrict__ batch,
                       float* __restrict__ cnt, int N) {
    int v = blockIdx.x * 256 + threadIdx.x;
    if (v < N) {
        float d = deg_dinv[v] + 1.0f;           // + self loop
        deg_dinv[v] = rsqrtf(d);
        atomicAdd(&cnt[batch[v]], 1.0f);
    }
}

// agg1[v] = dinv[v]^2 * x[v]   (self-loop term)
__global__ void k_selfinit(const float4* __restrict__ x4, const float* __restrict__ dinv,
                           float4* __restrict__ agg1, int N) {
    int t = blockIdx.x * 256 + threadIdx.x;
    if (t < N * 16) {
        int v = t >> 4;
        float w = dinv[v]; w = w * w;
        float4 xv = x4[t];
        float4 o; o.x = w * xv.x; o.y = w * xv.y; o.z = w * xv.z; o.w = w * xv.w;
        agg1[t] = o;
    }
}

// agg1[dst] += dinv[s]*dinv[d] * x[src]
__global__ void k_scatter1(const int* __restrict__ src, const int* __restrict__ dst,
                           const float* __restrict__ dinv, const float4* __restrict__ x4,
                           float* __restrict__ agg1, int E) {
    int t = blockIdx.x * 256 + threadIdx.x;
    if (t < E * 16) {
        int e = t >> 4, c = t & 15;
        int s = src[e], d = dst[e];
        float w = dinv[s] * dinv[d];
        float4 xv = x4[s * 16 + c];
        float* p = &agg1[d * 64 + c * 4];
        atomicAdd(p + 0, w * xv.x);
        atomicAdd(p + 1, w * xv.y);
        atomicAdd(p + 2, w * xv.z);
        atomicAdd(p + 3, w * xv.w);
    }
}

// out = relu(A @ W + b), A:[N,64], W:[64,64]; in-place safe (tile staged in LDS first)
__global__ __launch_bounds__(256) void k_gemm64_relu(const float* __restrict__ A,
                                                     const float* __restrict__ W,
                                                     const float* __restrict__ bias,
                                                     float* __restrict__ out) {
    __shared__ float As[64][65];
    __shared__ float Ws[64][64];
    __shared__ float bs[64];
    int tid = threadIdx.x;
    int r0 = blockIdx.x * 64;

    {   // stage A tile (64x64) and W (64x64)
        int r = tid >> 2, cg = tid & 3;
        const float4* A4 = (const float4*)(A + (size_t)(r0 + r) * 64);
#pragma unroll
        for (int i = 0; i < 4; i++) {
            float4 a = A4[cg + 4 * i];
            int c = (cg + 4 * i) * 4;
            As[r][c + 0] = a.x; As[r][c + 1] = a.y; As[r][c + 2] = a.z; As[r][c + 3] = a.w;
        }
        const float4* W4 = (const float4*)W;
#pragma unroll
        for (int i = 0; i < 4; i++) {
            int idx = tid + 256 * i;
            float4 w = W4[idx];
            int k = idx >> 4, c = (idx & 15) * 4;
            *(float4*)&Ws[k][c] = w;
        }
        if (tid < 64) bs[tid] = bias[tid];
    }
    __syncthreads();

    int ty = tid >> 4, tx = tid & 15;
    float acc[4][4] = {};
#pragma unroll 16
    for (int kk = 0; kk < 64; kk++) {
        float4 wv = *(const float4*)&Ws[kk][tx * 4];
        float a0 = As[ty * 4 + 0][kk];
        float a1 = As[ty * 4 + 1][kk];
        float a2 = As[ty * 4 + 2][kk];
        float a3 = As[ty * 4 + 3][kk];
        acc[0][0] += a0 * wv.x; acc[0][1] += a0 * wv.y; acc[0][2] += a0 * wv.z; acc[0][3] += a0 * wv.w;
        acc[1][0] += a1 * wv.x; acc[1][1] += a1 * wv.y; acc[1][2] += a1 * wv.z; acc[1][3] += a1 * wv.w;
        acc[2][0] += a2 * wv.x; acc[2][1] += a2 * wv.y; acc[2][2] += a2 * wv.z; acc[2][3] += a2 * wv.w;
        acc[3][0] += a3 * wv.x; acc[3][1] += a3 * wv.y; acc[3][2] += a3 * wv.z; acc[3][3] += a3 * wv.w;
    }
#pragma unroll
    for (int i = 0; i < 4; i++) {
        float4 o;
        o.x = fmaxf(acc[i][0] + bs[tx * 4 + 0], 0.f);
        o.y = fmaxf(acc[i][1] + bs[tx * 4 + 1], 0.f);
        o.z = fmaxf(acc[i][2] + bs[tx * 4 + 2], 0.f);
        o.w = fmaxf(acc[i][3] + bs[tx * 4 + 3], 0.f);
        *(float4*)&out[(size_t)(r0 + ty * 4 + i) * 64 + tx * 4] = o;
    }
}

// aggP[batch[v]] += dinv[v]^2 * h[v]   (self loops of conv2, pooled)
__global__ void k_scatterP_nodes(const float4* __restrict__ h4, const float* __restrict__ dinv,
                                 const int* __restrict__ batch, float* __restrict__ aggP, int N) {
    int t = blockIdx.x * 256 + threadIdx.x;
    if (t < N * 16) {
        int v = t >> 4, c = t & 15;
        float w = dinv[v]; w = w * w;
        int g = batch[v];
        float4 h = h4[t];
        float* p = &aggP[g * 64 + c * 4];
        atomicAdd(p + 0, w * h.x);
        atomicAdd(p + 1, w * h.y);
        atomicAdd(p + 2, w * h.z);
        atomicAdd(p + 3, w * h.w);
    }
}

// aggP[batch[dst]] += dinv[s]*dinv[d] * h[src]
__global__ void k_scatterP_edges(const int* __restrict__ src, const int* __restrict__ dst,
                                 const float* __restrict__ dinv, const int* __restrict__ batch,
                                 const float4* __restrict__ h4, float* __restrict__ aggP, int E) {
    int t = blockIdx.x * 256 + threadIdx.x;
    if (t < E * 16) {
        int e = t >> 4, c = t & 15;
        int s = src[e], d = dst[e];
        float w = dinv[s] * dinv[d];
        int g = batch[d];
        float4 h = h4[s * 16 + c];
        float* p = &aggP[g * 64 + c * 4];
        atomicAdd(p + 0, w * h.x);
        atomicAdd(p + 1, w * h.y);
        atomicAdd(p + 2, w * h.z);
        atomicAdd(p + 3, w * h.w);
    }
}

// fold all trailing affine layers into u[1024], v[64], scalar C
__global__ void k_precompute(const float* __restrict__ fc1_W, const float* __restrict__ fc1_b,
                             const float* __restrict__ fcf_W, const float* __restrict__ fcf_b,
                             const float* __restrict__ gcn_fc_W, const float* __restrict__ gcn_fc_b,
                             const float* __restrict__ conv2_W, const float* __restrict__ conv2_b,
                             const float* __restrict__ emb_W2, const float* __restrict__ emb_b2,
                             float* __restrict__ vv, float* __restrict__ uu, float* __restrict__ Cc) {
    __shared__ float t1s[128], t2s[128];
    int tid = threadIdx.x;
    if (tid < 128) {                       // t1 = fc1_W @ fcf_W
        float s = 0;
        for (int j = 0; j < 64; j++) s += fc1_W[tid * 64 + j] * fcf_W[j];
        t1s[tid] = s;
    }
    __syncthreads();
    if (tid < 128) {                       // t2 = gcn_fc_W @ t1[64:]
        float s = 0;
        for (int m = 0; m < 64; m++) s += gcn_fc_W[tid * 64 + m] * t1s[64 + m];
        t2s[tid] = s;
    }
    __syncthreads();
    if (tid < 64) {                        // v = conv2_W @ t2
        float s = 0;
        for (int p = 0; p < 128; p++) s += conv2_W[tid * 128 + p] * t2s[p];
        vv[tid] = s;
    }
    for (int j = tid; j < 1024; j += 256) {  // u = emb_W2 @ t1[:64]
        float s = 0;
        for (int k = 0; k < 64; k++) s += emb_W2[j * 64 + k] * t1s[k];
        uu[j] = s;
    }
    if (tid == 0) {
        float c = fcf_b[0];
        for (int j = 0; j < 64; j++)  c += fc1_b[j] * fcf_W[j];
        for (int k = 0; k < 64; k++)  c += emb_b2[k] * t1s[k];
        for (int p = 0; p < 128; p++) c += conv2_b[p] * t2s[p];
        for (int m = 0; m < 64; m++)  c += gcn_fc_b[m] * t1s[64 + m];
        Cc[0] = c;
    }
}

// out[b] = (aggP[b]·v)/max(cnt,1) + C
__global__ void k_ginit(const float* __restrict__ aggP, const float* __restrict__ cnt,
                        const float* __restrict__ vv, const float* __restrict__ Cc,
                        float* __restrict__ out, int B) {
    int b = blockIdx.x * 256 + threadIdx.x;
    if (b < B) {
        float s = 0;
        for (int f = 0; f < 64; f++) s += aggP[b * 64 + f] * vv[f];
        float c = cnt[b]; c = c < 1.f ? 1.f : c;
        out[b] = s / c + Cc[0];
    }
}

// out[b] += sum_j relu(smiles[b]·W1[:,j] + b1[j]) * u[j]
// A:[4096,768], Bm:[768,1024]; tiles 64x64, K-step 16
__global__ __launch_bounds__(256) void k_embgemm(const float* __restrict__ A,
                                                 const float* __restrict__ Bm,
                                                 const float* __restrict__ b1,
                                                 const float* __restrict__ uu,
                                                 float* __restrict__ out) {
    __shared__ float As[16][68];   // k-major, padded
    __shared__ float Bs[16][64];
    int tid = threadIdx.x;
    int r0 = blockIdx.x * 64, n0 = blockIdx.y * 64;
    int ty = tid >> 4, tx = tid & 15;
    float acc[4][4] = {};

    for (int k0 = 0; k0 < 768; k0 += 16) {
        {   // A tile: 64 rows x 16 k
            int r = tid >> 2, kg = tid & 3;
            float4 a = *(const float4*)&A[(size_t)(r0 + r) * 768 + k0 + kg * 4];
            As[kg * 4 + 0][r] = a.x; As[kg * 4 + 1][r] = a.y;
            As[kg * 4 + 2][r] = a.z; As[kg * 4 + 3][r] = a.w;
            // B tile: 16 k x 64 cols
            float4 b = *(const float4*)&Bm[(size_t)(k0 + (tid >> 4)) * 1024 + n0 + (tid & 15) * 4];
            *(float4*)&Bs[tid >> 4][(tid & 15) * 4] = b;
        }
        __syncthreads();
#pragma unroll
        for (int kk = 0; kk < 16; kk++) {
            float4 av = *(const float4*)&As[kk][ty * 4];
            float4 bv = *(const float4*)&Bs[kk][tx * 4];
            acc[0][0] += av.x * bv.x; acc[0][1] += av.x * bv.y; acc[0][2] += av.x * bv.z; acc[0][3] += av.x * bv.w;
            acc[1][0] += av.y * bv.x; acc[1][1] += av.y * bv.y; acc[1][2] += av.y * bv.z; acc[1][3] += av.y * bv.w;
            acc[2][0] += av.z * bv.x; acc[2][1] += av.z * bv.y; acc[2][2] += av.z * bv.z; acc[2][3] += av.z * bv.w;
            acc[3][0] += av.w * bv.x; acc[3][1] += av.w * bv.y; acc[3][2] += av.w * bv.z; acc[3][3] += av.w * bv.w;
        }
        __syncthreads();
    }

#pragma unroll
    for (int i = 0; i < 4; i++) {
        float p = 0;
#pragma unroll
        for (int j = 0; j < 4; j++) {
            int col = n0 + tx * 4 + j;
            float pre = acc[i][j] + b1[col];
            p += fmaxf(pre, 0.f) * uu[col];
        }
#pragma unroll
        for (int m = 1; m < 16; m <<= 1) p += __shfl_xor(p, m);
        if (tx == 0) atomicAdd(&out[r0 + ty * 4 + i], p);
    }
}

// ---------------- launcher ----------------

extern "C" void kernel_launch(void* const* d_in, const int* in_sizes, int n_in,
                              void* d_out, int out_size, void* d_ws, size_t ws_size,
                              hipStream_t stream) {
    const float* smiles  = (const float*)d_in[0];
    const float* x       = (const float*)d_in[1];
    const int*   ei      = (const int*)d_in[2];
    const int*   batch   = (const int*)d_in[3];
    const float* emb_W1  = (const float*)d_in[4];
    const float* emb_b1  = (const float*)d_in[5];
    const float* emb_W2  = (const float*)d_in[6];
    const float* emb_b2  = (const float*)d_in[7];
    const float* conv1_W = (const float*)d_in[8];
    const float* conv1_b = (const float*)d_in[9];
    const float* conv2_W = (const float*)d_in[10];
    const float* conv2_b = (const float*)d_in[11];
    const float* gcn_fc_W = (const float*)d_in[12];
    const float* gcn_fc_b = (const float*)d_in[13];
    const float* fc1_W   = (const float*)d_in[14];
    const float* fc1_b   = (const float*)d_in[15];
    const float* fcf_W   = (const float*)d_in[16];
    const float* fcf_b   = (const float*)d_in[17];

    const int N = in_sizes[3];          // 131072
    const int E = in_sizes[2] / 2;      // 2097152
    const int B = in_sizes[0] / 768;    // 4096

    float* ws   = (float*)d_ws;
    float* deg  = ws;                   // N  (becomes dinv)
    float* cnt  = deg + N;              // B
    float* aggP = cnt + B;              // B*64
    float* vv   = aggP + (size_t)B * 64;  // 64
    float* uu   = vv + 64;              // 1024
    float* Cc   = uu + 1024;            // 1 (pad 16)
    float* agg1 = Cc + 16;              // N*64  (becomes h1r in place)

    const int* esrc = ei;
    const int* edst = ei + E;

    hipMemsetAsync(ws, 0, (size_t)(N + B + (size_t)B * 64) * sizeof(float), stream);

    k_deg<<<(E + 255) / 256, 256, 0, stream>>>(edst, deg, E);
    k_node<<<(N + 255) / 256, 256, 0, stream>>>(deg, batch, cnt, N);
    k_selfinit<<<(N * 16 + 255) / 256, 256, 0, stream>>>((const float4*)x, deg, (float4*)agg1, N);
    k_scatter1<<<(E * 16 + 255) / 256, 256, 0, stream>>>(esrc, edst, deg, (const float4*)x, agg1, E);
    k_gemm64_relu<<<N / 64, 256, 0, stream>>>(agg1, conv1_W, conv1_b, agg1);
    k_scatterP_nodes<<<(N * 16 + 255) / 256, 256, 0, stream>>>((const float4*)agg1, deg, batch, aggP, N);
    k_scatterP_edges<<<(E * 16 + 255) / 256, 256, 0, stream>>>(esrc, edst, deg, batch,
                                                               (const float4*)agg1, aggP, E);
    k_precompute<<<1, 256, 0, stream>>>(fc1_W, fc1_b, fcf_W, fcf_b, gcn_fc_W, gcn_fc_b,
                                        conv2_W, conv2_b, emb_W2, emb_b2, vv, uu, Cc);
    k_ginit<<<(B + 255) / 256, 256, 0, stream>>>(aggP, cnt, vv, Cc, (float*)d_out, B);
    k_embgemm<<<dim3(B / 64, 16), 256, 0, stream>>>(smiles, emb_W1, emb_b1, uu, (float*)d_out);
}

// Round 2
// 544.998 us; speedup vs baseline: 7.2202x; 7.2202x over previous
//
#include <hip/hip_runtime.h>

// ---------------- kernels ----------------

// degree histogram (in-degree at dst)
__global__ void k_deg(const int* __restrict__ dst, int* __restrict__ degi, int E) {
    int e = blockIdx.x * 256 + threadIdx.x;
    if (e < E) atomicAdd(&degi[dst[e]], 1);
}

// dinv = rsqrt(deg+1); per-graph node counts; per-block degree sums for scan
__global__ __launch_bounds__(256) void k_blocksum(const int* __restrict__ degi,
                                                  const int* __restrict__ batch,
                                                  float* __restrict__ dinv,
                                                  float* __restrict__ cnt,
                                                  int* __restrict__ bsum) {
    __shared__ int red[256];
    int tid = threadIdx.x;
    int v = blockIdx.x * 256 + tid;
    int dg = degi[v];
    dinv[v] = rsqrtf((float)dg + 1.0f);
    atomicAdd(&cnt[batch[v]], 1.0f);
    red[tid] = dg;
    __syncthreads();
    for (int s = 128; s > 0; s >>= 1) {
        if (tid < s) red[tid] += red[tid + s];
        __syncthreads();
    }
    if (tid == 0) bsum[blockIdx.x] = red[0];
}

// exclusive scan of 512 block sums
__global__ void k_scan1(const int* __restrict__ bsum, int* __restrict__ boff) {
    __shared__ int tmp[512];
    int tid = threadIdx.x;
    int v = bsum[tid];
    tmp[tid] = v;
    for (int d = 1; d < 512; d <<= 1) {
        __syncthreads();
        int t = (tid >= d) ? tmp[tid - d] : 0;
        __syncthreads();
        tmp[tid] += t;
    }
    boff[tid] = tmp[tid] - v;   // exclusive
}

// per-node exclusive offsets; init cursors
__global__ __launch_bounds__(256) void k_offsets(const int* __restrict__ degi,
                                                 const int* __restrict__ boff,
                                                 int* __restrict__ off,
                                                 int* __restrict__ cursor) {
    __shared__ int tmp[256];
    int tid = threadIdx.x;
    int v = blockIdx.x * 256 + tid;
    int dg = degi[v];
    tmp[tid] = dg;
    for (int d = 1; d < 256; d <<= 1) {
        __syncthreads();
        int t = (tid >= d) ? tmp[tid - d] : 0;
        __syncthreads();
        tmp[tid] += t;
    }
    int excl = tmp[tid] - dg + boff[blockIdx.x];
    off[v] = excl;
    cursor[v] = excl;
}

// fill CSR (src indices only; weights recomputed at gather)
__global__ void k_fill(const int* __restrict__ src, const int* __restrict__ dst,
                       int* __restrict__ cursor, int* __restrict__ csr_s, int E) {
    int e = blockIdx.x * 256 + threadIdx.x;
    if (e < E) {
        int p = atomicAdd(&cursor[dst[e]], 1);
        csr_s[p] = src[e];
    }
}

// y = A @ W  (A:[N,64], W:[64,64], no bias/relu)
__global__ __launch_bounds__(256) void k_gemm64(const float* __restrict__ A,
                                                const float* __restrict__ W,
                                                float* __restrict__ out) {
    __shared__ float As[64][65];
    __shared__ float Ws[64][64];
    int tid = threadIdx.x;
    int r0 = blockIdx.x * 64;
    {
        int r = tid >> 2, cg = tid & 3;
        const float4* A4 = (const float4*)(A + (size_t)(r0 + r) * 64);
#pragma unroll
        for (int i = 0; i < 4; i++) {
            float4 a = A4[cg + 4 * i];
            int c = (cg + 4 * i) * 4;
            As[r][c + 0] = a.x; As[r][c + 1] = a.y; As[r][c + 2] = a.z; As[r][c + 3] = a.w;
        }
        const float4* W4 = (const float4*)W;
#pragma unroll
        for (int i = 0; i < 4; i++) {
            int idx = tid + 256 * i;
            float4 w = W4[idx];
            int k = idx >> 4, c = (idx & 15) * 4;
            *(float4*)&Ws[k][c] = w;
        }
    }
    __syncthreads();
    int ty = tid >> 4, tx = tid & 15;
    float acc[4][4] = {};
#pragma unroll 16
    for (int kk = 0; kk < 64; kk++) {
        float4 wv = *(const float4*)&Ws[kk][tx * 4];
        float a0 = As[ty * 4 + 0][kk];
        float a1 = As[ty * 4 + 1][kk];
        float a2 = As[ty * 4 + 2][kk];
        float a3 = As[ty * 4 + 3][kk];
        acc[0][0] += a0 * wv.x; acc[0][1] += a0 * wv.y; acc[0][2] += a0 * wv.z; acc[0][3] += a0 * wv.w;
        acc[1][0] += a1 * wv.x; acc[1][1] += a1 * wv.y; acc[1][2] += a1 * wv.z; acc[1][3] += a1 * wv.w;
        acc[2][0] += a2 * wv.x; acc[2][1] += a2 * wv.y; acc[2][2] += a2 * wv.z; acc[2][3] += a2 * wv.w;
        acc[3][0] += a3 * wv.x; acc[3][1] += a3 * wv.y; acc[3][2] += a3 * wv.z; acc[3][3] += a3 * wv.w;
    }
#pragma unroll
    for (int i = 0; i < 4; i++) {
        float4 o;
        o.x = acc[i][0]; o.y = acc[i][1]; o.z = acc[i][2]; o.w = acc[i][3];
        *(float4*)&out[(size_t)(r0 + ty * 4 + i) * 64 + tx * 4] = o;
    }
}

// per-node gather of in-edges over y, + self-loop; relu(+b1) then dot with vv -> z[v]
__global__ __launch_bounds__(256) void k_gather(const float4* __restrict__ y4,
                                                const int* __restrict__ csr_s,
                                                const int* __restrict__ off,
                                                const int* __restrict__ degi,
                                                const float* __restrict__ dinv,
                                                const float4* __restrict__ b1_4,
                                                const float4* __restrict__ vv4,
                                                float* __restrict__ z) {
    int tid = threadIdx.x;
    int lane16 = tid & 15;
    int v = blockIdx.x * 16 + (tid >> 4);
    float dv = dinv[v];
    int base = off[v], ce = degi[v];
    float4 yv = y4[v * 16 + lane16];
    float w0 = dv * dv;
    float4 acc;
    acc.x = w0 * yv.x; acc.y = w0 * yv.y; acc.z = w0 * yv.z; acc.w = w0 * yv.w;
    for (int j = 0; j < ce; j++) {
        int s = csr_s[base + j];
        float w = dv * dinv[s];
        float4 ys = y4[s * 16 + lane16];
        acc.x += w * ys.x; acc.y += w * ys.y; acc.z += w * ys.z; acc.w += w * ys.w;
    }
    float4 b = b1_4[lane16];
    float4 vv = vv4[lane16];
    float p = fmaxf(acc.x + b.x, 0.f) * vv.x
            + fmaxf(acc.y + b.y, 0.f) * vv.y
            + fmaxf(acc.z + b.z, 0.f) * vv.z
            + fmaxf(acc.w + b.w, 0.f) * vv.w;
#pragma unroll
    for (int m = 1; m < 16; m <<= 1) p += __shfl_xor(p, m);
    if (lane16 == 0) z[v] = p;
}

// per-node second aggregation over scalar z; pool into out_g by graph
__global__ __launch_bounds__(256) void k_pass2(const float* __restrict__ z,
                                               const int* __restrict__ csr_s,
                                               const int* __restrict__ off,
                                               const int* __restrict__ degi,
                                               const float* __restrict__ dinv,
                                               const int* __restrict__ batch,
                                               float* __restrict__ out_g) {
    int v = blockIdx.x * 256 + threadIdx.x;
    float dv = dinv[v];
    int base = off[v], ce = degi[v];
    float acc = dv * dv * z[v];
    for (int j = 0; j < ce; j++) {
        int s = csr_s[base + j];
        acc += dv * dinv[s] * z[s];
    }
    atomicAdd(&out_g[batch[v]], acc);
}

// fold all trailing affine layers into u[1024], v[64], scalar C
__global__ void k_precompute(const float* __restrict__ fc1_W, const float* __restrict__ fc1_b,
                             const float* __restrict__ fcf_W, const float* __restrict__ fcf_b,
                             const float* __restrict__ gcn_fc_W, const float* __restrict__ gcn_fc_b,
                             const float* __restrict__ conv2_W, const float* __restrict__ conv2_b,
                             const float* __restrict__ emb_W2, const float* __restrict__ emb_b2,
                             float* __restrict__ vv, float* __restrict__ uu, float* __restrict__ Cc) {
    __shared__ float t1s[128], t2s[128];
    int tid = threadIdx.x;
    if (tid < 128) {
        float s = 0;
        for (int j = 0; j < 64; j++) s += fc1_W[tid * 64 + j] * fcf_W[j];
        t1s[tid] = s;
    }
    __syncthreads();
    if (tid < 128) {
        float s = 0;
        for (int m = 0; m < 64; m++) s += gcn_fc_W[tid * 64 + m] * t1s[64 + m];
        t2s[tid] = s;
    }
    __syncthreads();
    if (tid < 64) {
        float s = 0;
        for (int p = 0; p < 128; p++) s += conv2_W[tid * 128 + p] * t2s[p];
        vv[tid] = s;
    }
    for (int j = tid; j < 1024; j += 256) {
        float s = 0;
        for (int k = 0; k < 64; k++) s += emb_W2[j * 64 + k] * t1s[k];
        uu[j] = s;
    }
    if (tid == 0) {
        float c = fcf_b[0];
        for (int j = 0; j < 64; j++)  c += fc1_b[j] * fcf_W[j];
        for (int k = 0; k < 64; k++)  c += emb_b2[k] * t1s[k];
        for (int p = 0; p < 128; p++) c += conv2_b[p] * t2s[p];
        for (int m = 0; m < 64; m++)  c += gcn_fc_b[m] * t1s[64 + m];
        Cc[0] = c;
    }
}

// out[b] = out_g[b]/max(cnt,1) + C
__global__ void k_ginit(const float* __restrict__ out_g, const float* __restrict__ cnt,
                        const float* __restrict__ Cc, float* __restrict__ out, int B) {
    int b = blockIdx.x * 256 + threadIdx.x;
    if (b < B) {
        float c = cnt[b]; c = c < 1.f ? 1.f : c;
        out[b] = out_g[b] / c + Cc[0];
    }
}

// out[b] += sum_j relu(smiles[b]·W1[:,j] + b1[j]) * u[j]
__global__ __launch_bounds__(256) void k_embgemm(const float* __restrict__ A,
                                                 const float* __restrict__ Bm,
                                                 const float* __restrict__ b1,
                                                 const float* __restrict__ uu,
                                                 float* __restrict__ out) {
    __shared__ float As[16][68];
    __shared__ float Bs[16][64];
    int tid = threadIdx.x;
    int r0 = blockIdx.x * 64, n0 = blockIdx.y * 64;
    int ty = tid >> 4, tx = tid & 15;
    float acc[4][4] = {};

    for (int k0 = 0; k0 < 768; k0 += 16) {
        {
            int r = tid >> 2, kg = tid & 3;
            float4 a = *(const float4*)&A[(size_t)(r0 + r) * 768 + k0 + kg * 4];
            As[kg * 4 + 0][r] = a.x; As[kg * 4 + 1][r] = a.y;
            As[kg * 4 + 2][r] = a.z; As[kg * 4 + 3][r] = a.w;
            float4 b = *(const float4*)&Bm[(size_t)(k0 + (tid >> 4)) * 1024 + n0 + (tid & 15) * 4];
            *(float4*)&Bs[tid >> 4][(tid & 15) * 4] = b;
        }
        __syncthreads();
#pragma unroll
        for (int kk = 0; kk < 16; kk++) {
            float4 av = *(const float4*)&As[kk][ty * 4];
            float4 bv = *(const float4*)&Bs[kk][tx * 4];
            acc[0][0] += av.x * bv.x; acc[0][1] += av.x * bv.y; acc[0][2] += av.x * bv.z; acc[0][3] += av.x * bv.w;
            acc[1][0] += av.y * bv.x; acc[1][1] += av.y * bv.y; acc[1][2] += av.y * bv.z; acc[1][3] += av.y * bv.w;
            acc[2][0] += av.z * bv.x; acc[2][1] += av.z * bv.y; acc[2][2] += av.z * bv.z; acc[2][3] += av.z * bv.w;
            acc[3][0] += av.w * bv.x; acc[3][1] += av.w * bv.y; acc[3][2] += av.w * bv.z; acc[3][3] += av.w * bv.w;
        }
        __syncthreads();
    }

#pragma unroll
    for (int i = 0; i < 4; i++) {
        float p = 0;
#pragma unroll
        for (int j = 0; j < 4; j++) {
            int col = n0 + tx * 4 + j;
            float pre = acc[i][j] + b1[col];
            p += fmaxf(pre, 0.f) * uu[col];
        }
#pragma unroll
        for (int m = 1; m < 16; m <<= 1) p += __shfl_xor(p, m);
        if (tx == 0) atomicAdd(&out[r0 + ty * 4 + i], p);
    }
}

// ---------------- launcher ----------------

extern "C" void kernel_launch(void* const* d_in, const int* in_sizes, int n_in,
                              void* d_out, int out_size, void* d_ws, size_t ws_size,
                              hipStream_t stream) {
    const float* smiles  = (const float*)d_in[0];
    const float* x       = (const float*)d_in[1];
    const int*   ei      = (const int*)d_in[2];
    const int*   batch   = (const int*)d_in[3];
    const float* emb_W1  = (const float*)d_in[4];
    const float* emb_b1  = (const float*)d_in[5];
    const float* emb_W2  = (const float*)d_in[6];
    const float* emb_b2  = (const float*)d_in[7];
    const float* conv1_W = (const float*)d_in[8];
    const float* conv1_b = (const float*)d_in[9];
    const float* conv2_W = (const float*)d_in[10];
    const float* conv2_b = (const float*)d_in[11];
    const float* gcn_fc_W = (const float*)d_in[12];
    const float* gcn_fc_b = (const float*)d_in[13];
    const float* fc1_W   = (const float*)d_in[14];
    const float* fc1_b   = (const float*)d_in[15];
    const float* fcf_W   = (const float*)d_in[16];
    const float* fcf_b   = (const float*)d_in[17];

    const int N = in_sizes[3];          // 131072
    const int E = in_sizes[2] / 2;      // 2097152
    const int B = in_sizes[0] / 768;    // 4096

    // workspace layout (all 4-byte elems; offsets stay 16B-aligned)
    char* w = (char*)d_ws;
    int*   degi   = (int*)w;                    w += (size_t)N * 4;
    float* cnt    = (float*)w;                  w += (size_t)B * 4;
    float* out_g  = (float*)w;                  w += (size_t)B * 4;
    float* dinv   = (float*)w;                  w += (size_t)N * 4;
    int*   bsum   = (int*)w;                    w += 1024 * 4;
    int*   boff   = (int*)w;                    w += 1024 * 4;
    int*   off    = (int*)w;                    w += (size_t)N * 4;
    int*   cursor = (int*)w;                    w += (size_t)N * 4;
    float* z      = (float*)w;                  w += (size_t)N * 4;
    float* vv     = (float*)w;                  w += 64 * 4;
    float* uu     = (float*)w;                  w += 1024 * 4;
    float* Cc     = (float*)w;                  w += 32 * 4;
    int*   csr_s  = (int*)w;                    w += (size_t)E * 4;
    float* y      = (float*)w;                  /* N*64 floats */

    const int* esrc = ei;
    const int* edst = ei + E;

    // zero degi | cnt | out_g (contiguous)
    hipMemsetAsync(degi, 0, (size_t)(N + 2 * B) * 4, stream);

    k_deg<<<(E + 255) / 256, 256, 0, stream>>>(edst, degi, E);
    k_blocksum<<<N / 256, 256, 0, stream>>>(degi, batch, dinv, cnt, bsum);
    k_scan1<<<1, 512, 0, stream>>>(bsum, boff);
    k_offsets<<<N / 256, 256, 0, stream>>>(degi, boff, off, cursor);
    k_fill<<<(E + 255) / 256, 256, 0, stream>>>(esrc, edst, cursor, csr_s, E);
    k_gemm64<<<N / 64, 256, 0, stream>>>(x, conv1_W, y);
    k_precompute<<<1, 256, 0, stream>>>(fc1_W, fc1_b, fcf_W, fcf_b, gcn_fc_W, gcn_fc_b,
                                        conv2_W, conv2_b, emb_W2, emb_b2, vv, uu, Cc);
    k_gather<<<N / 16, 256, 0, stream>>>((const float4*)y, csr_s, off, degi, dinv,
                                         (const float4*)conv1_b, (const float4*)vv, z);
    k_pass2<<<N / 256, 256, 0, stream>>>(z, csr_s, off, degi, dinv, batch, out_g);
    k_ginit<<<(B + 255) / 256, 256, 0, stream>>>(out_g, cnt, Cc, (float*)d_out, B);
    k_embgemm<<<dim3(B / 64, 16), 256, 0, stream>>>(smiles, emb_W1, emb_b1, uu, (float*)d_out);
}